// Round 8
// baseline (544.436 us; speedup 1.0000x reference)
//
#include <hip/hip_runtime.h>
#include <hip/hip_bf16.h>

#define TTLEN 2048
#define NCH   64
#define CLEN  32    // TTLEN / NCH
#define NBLK  512   // persistent grid; 2 blocks/CU by LDS (64KiB), guide-sanctioned k=2

typedef unsigned short ushort_t;
typedef __attribute__((ext_vector_type(8))) short short8;
typedef __attribute__((ext_vector_type(4))) float f32x4;

__device__ __forceinline__ unsigned short f2bf(float f) {
    __hip_bfloat16 h = __float2bfloat16(f);
    return *reinterpret_cast<unsigned short*>(&h);
}
__device__ __forceinline__ float bf2f(unsigned int u16) {
    union { unsigned int i; float f; } v; v.i = u16 << 16; return v.f;
}

#define GLD_LDS16(gp, lp) __builtin_amdgcn_global_load_lds( \
    (const __attribute__((address_space(1))) void*)(gp),    \
    (__attribute__((address_space(3))) void*)(lp), 16, 0, 0)

// ---- software grid barrier: device-scope atomics + agent fences (G16 pattern) ----
// bar[0] = arrive count, bar[1] = generation. Zeroed by hipMemsetAsync pre-launch.
// gen is read BEFORE arriving; flip only possible after all NBLK arrive -> no race.
__device__ __forceinline__ void gbar(unsigned int* bar) {
    __threadfence();                       // release: my writes -> coherent point
    __syncthreads();                       // whole block arrived (drains vm/lgkm)
    if (threadIdx.x == 0) {
        unsigned int g = atomicAdd(&bar[1], 0u);
        if (atomicAdd(&bar[0], 1u) == NBLK - 1u) {
            bar[0] = 0u;                   // safe: all arrived, none reads cnt till flip
            __threadfence();
            atomicAdd(&bar[1], 1u);        // flip generation
        } else {
            while (atomicAdd(&bar[1], 0u) == g) __builtin_amdgcn_s_sleep(2);
        }
        __threadfence();                   // acquire: invalidate stale cache lines
    }
    __syncthreads();
}

// ================== single persistent kernel, 5 phases ==================
// Phase 2/5 GEMM = r6-verified: 2-buffer LDS ping-pong, counted vmcnt(8),
// raw s_barrier, LDS-repack dwordx4 epilogue, M-fast job order.
// Scans = r0/r5-verified shapes. Phase bodies byte-identical to r7.
__global__ void __launch_bounds__(256, 2)
rwkv_fused(const float* __restrict__ x,   const float* __restrict__ tw,
           const float* __restrict__ ta,  const float* __restrict__ tb,
           const float* __restrict__ tg,  const float* __restrict__ tmk,
           const float* __restrict__ tmv, const float* __restrict__ tmr,
           const float* __restrict__ Wk,  const float* __restrict__ bk,
           const float* __restrict__ Wv,  const float* __restrict__ bv,
           const float* __restrict__ Wr,  const float* __restrict__ br,
           const float* __restrict__ Wo,  const float* __restrict__ bo,
           ushort_t* __restrict__ Wall,   ushort_t* __restrict__ Wob,
           ushort_t* __restrict__ xk,     ushort_t* __restrict__ xv,
           ushort_t* __restrict__ xr,     ushort_t* __restrict__ kb,
           ushort_t* __restrict__ vb,     ushort_t* __restrict__ rb,
           float* __restrict__ Sloc,      float* __restrict__ Kloc,
           float* __restrict__ outp,      unsigned int* bar) {
    __shared__ alignas(16) ushort_t sh[2][2 * 128 * 64];   // 64 KiB
    const int bid = blockIdx.x;
    const int tid = threadIdx.x;

    // ---------------- phase 1: mix3 (jobs 0..8191) + weight convert (8192..9215) ----
    for (int job = bid; job < 9216; job += NBLK) {
        if (job >= 8192) {
            int bb = job - 8192;
            int m = bb >> 8;                           // 0..3
            const float* src = (m == 0) ? Wk : (m == 1) ? Wv : (m == 2) ? Wr : Wo;
            ushort_t* dst = (m == 3) ? Wob : Wall + (size_t)m * 262144;
            int i = (bb & 255) * 256 + tid;            // group of 4
            float4 v = *(const float4*)(src + (size_t)i * 4);
            union { unsigned short u[4]; uint2 p; } pk;
            pk.u[0] = f2bf(v.x); pk.u[1] = f2bf(v.y);
            pk.u[2] = f2bf(v.z); pk.u[3] = f2bf(v.w);
            *(uint2*)(dst + (size_t)i * 4) = pk.p;
            continue;
        }
        int i   = job * 256 + tid;                     // group of 4 channels
        int c4  = (i & 127) << 2;
        int row = i >> 7;                              // b*T + t
        int t   = row & (TTLEN - 1);
        float4 xc = *(const float4*)(x + (size_t)row * 512 + c4);
        float4 xp = make_float4(0.f, 0.f, 0.f, 0.f);
        if (t != 0) xp = *(const float4*)(x + (size_t)(row - 1) * 512 + c4);
        size_t o = (size_t)row * 512 + c4;
        union { unsigned short u[4]; uint2 p; } pk;
        {
            float4 tv = *(const float4*)(tmk + c4);
            pk.u[0] = f2bf(xc.x * tv.x + xp.x * (1.f - tv.x));
            pk.u[1] = f2bf(xc.y * tv.y + xp.y * (1.f - tv.y));
            pk.u[2] = f2bf(xc.z * tv.z + xp.z * (1.f - tv.z));
            pk.u[3] = f2bf(xc.w * tv.w + xp.w * (1.f - tv.w));
            *(uint2*)(xk + o) = pk.p;
        }
        {
            float4 tv = *(const float4*)(tmv + c4);
            pk.u[0] = f2bf(xc.x * tv.x + xp.x * (1.f - tv.x));
            pk.u[1] = f2bf(xc.y * tv.y + xp.y * (1.f - tv.y));
            pk.u[2] = f2bf(xc.z * tv.z + xp.z * (1.f - tv.z));
            pk.u[3] = f2bf(xc.w * tv.w + xp.w * (1.f - tv.w));
            *(uint2*)(xv + o) = pk.p;
        }
        {
            float4 tv = *(const float4*)(tmr + c4);
            pk.u[0] = f2bf(xc.x * tv.x + xp.x * (1.f - tv.x));
            pk.u[1] = f2bf(xc.y * tv.y + xp.y * (1.f - tv.y));
            pk.u[2] = f2bf(xc.z * tv.z + xp.z * (1.f - tv.z));
            pk.u[3] = f2bf(xc.w * tv.w + xp.w * (1.f - tv.w));
            *(uint2*)(xr + o) = pk.p;
        }
    }
    gbar(bar);

    const int lane = tid & 63;
    const int w    = tid >> 6;
    const int wm   = (w >> 1) << 6;
    const int wn   = (w & 1) << 6;
    const int r16  = lane & 15, q = lane >> 4;
    const int rowInW = lane >> 3, ch = lane & 7;

#define STAGE(buf, k0) {                                                        \
    const ushort_t* Ag = Abase + (k0);                                          \
    const ushort_t* Bg = Bbase + (k0);                                          \
    ushort_t* As_ = &sh[buf][0];                                                \
    ushort_t* Bs_ = &sh[buf][128 * 64];                                         \
    _Pragma("unroll")                                                           \
    for (int i = 0; i < 4; ++i) {                                               \
        int baseRow = w * 32 + i * 8;                                           \
        int row = baseRow + rowInW;                                             \
        int gch = ch ^ (row & 7);                                               \
        GLD_LDS16(Ag + (size_t)row * 512 + gch * 8, &As_[baseRow * 64]);        \
        GLD_LDS16(Bg + (size_t)row * 512 + gch * 8, &Bs_[baseRow * 64]);        \
    }                                                                           \
}
#define KLOOP() {                                                               \
    STAGE(0, 0);                                                                \
    _Pragma("unroll")                                                           \
    for (int k = 0; k < 8; ++k) {                                               \
        const int cur = k & 1;                                                  \
        if (k < 7) {                                                            \
            STAGE(cur ^ 1, (k + 1) * 64);                                       \
            asm volatile("s_waitcnt vmcnt(8)" ::: "memory");                    \
        } else {                                                                \
            asm volatile("s_waitcnt vmcnt(0)" ::: "memory");                    \
        }                                                                       \
        __builtin_amdgcn_s_barrier();                                           \
        __builtin_amdgcn_sched_barrier(0);                                      \
        {                                                                       \
            const ushort_t* As = &sh[cur][0];                                   \
            const ushort_t* Bs = &sh[cur][128 * 64];                            \
            _Pragma("unroll")                                                   \
            for (int s = 0; s < 2; ++s) {                                       \
                short8 af[4], bfr[4];                                           \
                _Pragma("unroll")                                               \
                for (int mt = 0; mt < 4; ++mt) {                                \
                    int row = wm + mt * 16 + r16;                               \
                    af[mt] = *(const short8*)(&As[row * 64 +                    \
                                (((s * 4 + q) ^ (r16 & 7)) << 3)]);             \
                }                                                               \
                _Pragma("unroll")                                               \
                for (int nt = 0; nt < 4; ++nt) {                                \
                    int row = wn + nt * 16 + r16;                               \
                    bfr[nt] = *(const short8*)(&Bs[row * 64 +                   \
                                (((s * 4 + q) ^ (r16 & 7)) << 3)]);             \
                }                                                               \
                _Pragma("unroll")                                               \
                for (int mt = 0; mt < 4; ++mt)                                  \
                    _Pragma("unroll")                                           \
                    for (int nt = 0; nt < 4; ++nt)                              \
                        acc[mt][nt] = __builtin_amdgcn_mfma_f32_16x16x32_bf16(  \
                            af[mt], bfr[nt], acc[mt][nt], 0, 0, 0);             \
            }                                                                   \
        }                                                                       \
        __builtin_amdgcn_sched_barrier(0);                                      \
        __builtin_amdgcn_s_barrier();                                           \
    }                                                                           \
}

    // ---------------- phase 2: k/v/r GEMMs (1536 jobs, 3 per block) ----------------
    for (int job = bid; job < 1536; job += NBLK) {
        __syncthreads();                      // LDS reuse guard between jobs
        const int mBlk  = (job & 127) << 7;   // M fast
        const int nTile = job >> 7;           // 0..11
        const int p     = nTile >> 2;         // band: 0=k,1=v,2=r
        const int nBlk  = (nTile & 3) << 7;   // band-local col base
        const ushort_t* A   = (p == 0) ? xk : (p == 1) ? xv : xr;
        const float* bias   = (p == 0) ? bk : (p == 1) ? bv : br;
        ushort_t* outb      = (p == 0) ? kb : (p == 1) ? vb : rb;
        const ushort_t* Abase = A + (size_t)mBlk * 512;
        const ushort_t* Bbase = Wall + (size_t)p * 262144 + (size_t)nBlk * 512;

        f32x4 acc[4][4];
#pragma unroll
        for (int a = 0; a < 4; ++a)
#pragma unroll
            for (int b = 0; b < 4; ++b) acc[a][b] = (f32x4){0.f, 0.f, 0.f, 0.f};

        KLOOP();

        // epilogue: activated bf16 subtile -> LDS repack -> dwordx4 stores
        const int nLocal0 = nBlk + wn;
        ushort_t* shf = &sh[0][0];
        const int wbase = w << 12;            // 8KB per wave
#pragma unroll
        for (int nt = 0; nt < 4; ++nt) {
            float bv_ = bias[nLocal0 + nt * 16 + r16];
#pragma unroll
            for (int mt = 0; mt < 4; ++mt) {
#pragma unroll
                for (int i = 0; i < 4; ++i) {
                    int rl = mt * 16 + (q << 2) + i;     // wave-local row 0..63
                    int cl = nt * 16 + r16;              // wave-local col 0..63
                    float v = acc[mt][nt][i] + bv_;
                    if (p == 0) v = __expf(fminf(fmaxf(v, -60.f), 30.f));
                    else if (p == 2) v = 1.f / (1.f + __expf(-v));
                    shf[wbase + rl * 64 + (cl ^ (((rl >> 2) & 3) << 4))] = f2bf(v);
                }
            }
        }
        asm volatile("s_waitcnt lgkmcnt(0)" ::: "memory");
        __builtin_amdgcn_sched_barrier(0);
#pragma unroll
        for (int i = 0; i < 8; ++i) {
            int c   = i * 64 + lane;                 // chunk id 0..511
            int rl  = c >> 3;
            int cl8 = (c & 7) << 3;
            short8 val = *(const short8*)(
                &shf[wbase + rl * 64 + (cl8 ^ (((rl >> 2) & 3) << 4))]);
            int grow = mBlk + wm + rl;
            *(short8*)(&outb[(size_t)grow * 512 + nLocal0 + cl8]) = val;
        }
    }
    gbar(bar);

    // ---------------- phase 3: scanA (512 jobs, 1 per block) ----------------
    {
        int b = bid >> 6, j = bid & 63;
        int a0 = tid * 2;
        int h = a0 >> 6;
        float r = tw[h * TTLEN + TTLEN - 2];
        int t0 = j * CLEN;
        size_t base = ((size_t)(b * TTLEN + t0)) * 512 + a0;
        const float* al = ta + h * TTLEN + t0;
        float s0 = 0.f, s1 = 0.f, sk0 = 0.f, sk1 = 0.f;
#pragma unroll 8
        for (int it = 0; it < CLEN; ++it) {
            unsigned int kk = *(const unsigned int*)(kb + base + (size_t)it * 512);
            unsigned int vv = *(const unsigned int*)(vb + base + (size_t)it * 512);
            float kf0 = bf2f(kk & 0xffff), kf1 = bf2f(kk >> 16);
            float vf0 = bf2f(vv & 0xffff), vf1 = bf2f(vv >> 16);
            float av = al[it];
            sk0 += kf0; sk1 += kf1;
            s0 = fmaf(r, s0, av * kf0 * vf0);
            s1 = fmaf(r, s1, av * kf1 * vf1);
        }
        int o = (b * NCH + j) * 512 + a0;
        Sloc[o] = s0; Sloc[o + 1] = s1;
        Kloc[o] = sk0; Kloc[o + 1] = sk1;
    }
    gbar(bar);

    // ------- phase 4: scanB, in-block chunk-prefix + replay, emit rwkv (=xk) -------
    {
        int b = bid >> 6, j = bid & 63;
        int a0 = tid * 2;
        int h = a0 >> 6;
        float r = tw[h * TTLEN + TTLEN - 2];
        float rL = r;
#pragma unroll
        for (int i = 0; i < 5; ++i) rL *= rL;       // r^32 = r^CLEN
        float s0 = 0.f, s1 = 0.f, sk0 = 0.f, sk1 = 0.f;
#pragma unroll 4
        for (int jj = 0; jj < j; ++jj) {
            int oo = (b * NCH + jj) * 512 + a0;
            float2 sl = *(const float2*)(Sloc + oo);
            float2 kl = *(const float2*)(Kloc + oo);
            s0 = fmaf(rL, s0, sl.x);
            s1 = fmaf(rL, s1, sl.y);
            sk0 += kl.x; sk1 += kl.y;
        }
        int t0 = j * CLEN;
        size_t base = ((size_t)(b * TTLEN + t0)) * 512 + a0;
        const float* al = ta + h * TTLEN + t0;
        const float* bt = tb + h * TTLEN + t0;
#pragma unroll 4
        for (int it = 0; it < CLEN; ++it) {
            unsigned int kk = *(const unsigned int*)(kb + base + (size_t)it * 512);
            unsigned int vv = *(const unsigned int*)(vb + base + (size_t)it * 512);
            unsigned int rr = *(const unsigned int*)(rb + base + (size_t)it * 512);
            float kf0 = bf2f(kk & 0xffff), kf1 = bf2f(kk >> 16);
            float vf0 = bf2f(vv & 0xffff), vf1 = bf2f(vv >> 16);
            float rf0 = bf2f(rr & 0xffff), rf1 = bf2f(rr >> 16);
            float av = al[it], btv = bt[it];
            sk0 += kf0; sk1 += kf1;
            s0 = fmaf(r, s0, av * kf0 * vf0);
            s1 = fmaf(r, s1, av * kf1 * vf1);
            float w0 = btv * s0, w1 = btv * s1;
            unsigned int outw =
                ((unsigned int)f2bf(rf1 * w1 / sk1) << 16) | f2bf(rf0 * w0 / sk0);
            *(unsigned int*)(xk + base + (size_t)it * 512) = outw;   // rwkv = xk
        }
    }
    gbar(bar);

    // ---------------- phase 5: out-projection GEMM (512 jobs, 1 per block) ----------
    {
        __syncthreads();
        const int mBlk = (bid & 127) << 7;    // M fast
        const int nBlk = (bid >> 7) << 7;     // 0..3 tiles
        const ushort_t* Abase = xk + (size_t)mBlk * 512;   // rwkv
        const ushort_t* Bbase = Wob + (size_t)nBlk * 512;

        f32x4 acc[4][4];
#pragma unroll
        for (int a = 0; a < 4; ++a)
#pragma unroll
            for (int b = 0; b < 4; ++b) acc[a][b] = (f32x4){0.f, 0.f, 0.f, 0.f};

        KLOOP();

#pragma unroll
        for (int mt = 0; mt < 4; ++mt) {
#pragma unroll
            for (int nt = 0; nt < 4; ++nt) {
                int col = nBlk + wn + nt * 16 + r16;
                float bv_ = bo[col];
#pragma unroll
                for (int i = 0; i < 4; ++i) {
                    int row = mBlk + wm + mt * 16 + (q << 2) + i;
                    float v = (acc[mt][nt][i] + bv_) * tg[row & (TTLEN - 1)];
                    outp[(size_t)row * 512 + col] = v;
                }
            }
        }
    }
#undef KLOOP
#undef STAGE
}

extern "C" void kernel_launch(void* const* d_in, const int* in_sizes, int n_in,
                              void* d_out, int out_size, void* d_ws, size_t ws_size,
                              hipStream_t stream) {
    const float* x   = (const float*)d_in[0];
    const float* tw  = (const float*)d_in[1];
    const float* ta  = (const float*)d_in[2];
    const float* tb  = (const float*)d_in[3];
    const float* tg  = (const float*)d_in[4];
    const float* tmk = (const float*)d_in[5];
    const float* tmv = (const float*)d_in[6];
    const float* tmr = (const float*)d_in[7];
    const float* Wk  = (const float*)d_in[8];
    const float* bk  = (const float*)d_in[9];
    const float* Wv  = (const float*)d_in[10];
    const float* bv  = (const float*)d_in[11];
    const float* Wr  = (const float*)d_in[12];
    const float* br  = (const float*)d_in[13];
    const float* Wo  = (const float*)d_in[14];
    const float* bo  = (const float*)d_in[15];

    char* ws = (char*)d_ws;
    ushort_t* Wall = (ushort_t*)(ws + 0);            // [1536][512] bf16 (Wk;Wv;Wr)
    ushort_t* Wob  = (ushort_t*)(ws + 1572864);      // [512][512] bf16
    ushort_t* xk   = (ushort_t*)(ws + 2097152);      // 16.78 MB each; rwkv aliases xk
    ushort_t* xv   = (ushort_t*)(ws + 18874368);
    ushort_t* xr   = (ushort_t*)(ws + 35651584);
    ushort_t* kb   = (ushort_t*)(ws + 52428800);
    ushort_t* vb   = (ushort_t*)(ws + 69206016);
    ushort_t* rb   = (ushort_t*)(ws + 85983232);
    float* Sloc = (float*)(ws + 102760448);          // 1 MB each
    float* Kloc = (float*)(ws + 103809024);
    unsigned int* bar = (unsigned int*)(ws + 104857600);   // [cnt, gen]
    float* outp = (float*)d_out;

    hipMemsetAsync(bar, 0, 64, stream);              // barrier state: stream-ordered

    rwkv_fused<<<dim3(NBLK), dim3(256), 0, stream>>>(
        x, tw, ta, tb, tg, tmk, tmv, tmr, Wk, bk, Wv, bv, Wr, br, Wo, bo,
        Wall, Wob, xk, xv, xr, kb, vb, rb, Sloc, Kloc, outp, bar);
}